// Round 6
// baseline (346.815 us; speedup 1.0000x reference)
//
#include <hip/hip_runtime.h>

// y[b,h,l] = sum_{m<=l} x[b,h,m] k[h,l-m] + D[h] x[b,h,l]   (C = 1)
// One block per h (1024 threads, 8 complex elems/thread in registers).
// 8192-pt FFT as 5 register passes (radix-8 x4 + radix-2), 4 LDS exchanges.
// K = FFT(k) once -> kspec regs (pre-scaled 1/N). Batch pairs (0,1),(2,3)
// via z = x_b0 + i x_b1; ifft(FFT(z)*K) = y_b0 + i y_b1.
// Fusions: fwd pass 1 reads global (upper half zero); mid = fwd half=1 +
// pointwise + inv halves {1,2,4} in regs; last inv stage fused with epilogue.
//
// Resource model (r3-r5 lessons): any __launch_bounds__ 2nd arg OR the
// default occupancy heuristic for 1024-thread blocks pins VGPR=64 -> massive
// spills (~1.3 GB HBM scratch traffic). Fix: amdgpu_waves_per_eu(4,4)
// (4 waves/EU is all we can get with 64 KiB LDS anyway) + recompute per-pass
// twiddles locally so live-across-barrier state is ~35 regs.
#define Bdim 4
#define Hdim 1024
#define Ldim 4096
#define NFFT 8192
#define NTHR 1024
#define R2C 0.70710678118654752440f

// LDS float2-index swizzle: minimal-round b64 access for all strides used.
__device__ __forceinline__ int SW(int i) { return i ^ ((i >> 4) & 15); }

// v_sin_f32 / v_cos_f32 take input in REVOLUTIONS (D = sin(S0*2pi)).
__device__ __forceinline__ void sincos_rev(float f, float& s, float& c) {
#if __has_builtin(__builtin_amdgcn_sinf) && __has_builtin(__builtin_amdgcn_cosf)
    s = __builtin_amdgcn_sinf(f);
    c = __builtin_amdgcn_cosf(f);
#else
    __sincosf(f * 6.28318530717958647692f, &s, &c);
#endif
}

__device__ __forceinline__ float2 cadd(float2 a, float2 b) { return make_float2(a.x + b.x, a.y + b.y); }
__device__ __forceinline__ float2 csub(float2 a, float2 b) { return make_float2(a.x - b.x, a.y - b.y); }
__device__ __forceinline__ float2 cmul(float2 a, float2 b) {
    return make_float2(a.x * b.x - a.y * b.y, a.x * b.y + a.y * b.x);
}
__device__ __forceinline__ float2 cmuli(float2 a)    { return make_float2(-a.y, a.x); }  // a * (+i)
__device__ __forceinline__ float2 cmulnegi(float2 a) { return make_float2(a.y, -a.x); }  // a * (-i)

// ---- forward radix-8 (DIF halves {4s,2s,s}), w = exp(-2pi i (t mod s)/(8s)) ----
__device__ __forceinline__ void fwd8_bc(float2 e[8], float2 w) {
    float2 w2  = cmul(w, w);        // W_{4s}^{qm}
    float2 w2n = cmulnegi(w2);
    {   float2 u, d;
        u = e[0]; d = csub(u, e[2]); e[0] = cadd(u, e[2]); e[2] = cmul(d, w2);
        u = e[1]; d = csub(u, e[3]); e[1] = cadd(u, e[3]); e[3] = cmul(d, w2n);
        u = e[4]; d = csub(u, e[6]); e[4] = cadd(u, e[6]); e[6] = cmul(d, w2);
        u = e[5]; d = csub(u, e[7]); e[5] = cadd(u, e[7]); e[7] = cmul(d, w2n);
    }
    float2 w4 = cmul(w2, w2);       // W_{2s}^{qm}
    {   float2 u, d;
        u = e[0]; d = csub(u, e[1]); e[0] = cadd(u, e[1]); e[1] = cmul(d, w4);
        u = e[2]; d = csub(u, e[3]); e[2] = cadd(u, e[3]); e[3] = cmul(d, w4);
        u = e[4]; d = csub(u, e[5]); e[4] = cadd(u, e[5]); e[5] = cmul(d, w4);
        u = e[6]; d = csub(u, e[7]); e[6] = cadd(u, e[7]); e[7] = cmul(d, w4);
    }
}
__device__ __forceinline__ void fwd8(float2 e[8], float2 w) {
    float2 w1  = make_float2(R2C * (w.x + w.y), R2C * (w.y - w.x)); // w*W8^1
    float2 w2t = cmulnegi(w);                                        // w*W8^2
    float2 w3  = cmulnegi(w1);                                       // w*W8^3
    {   float2 u, d;
        u = e[0]; d = csub(u, e[4]); e[0] = cadd(u, e[4]); e[4] = cmul(d, w);
        u = e[1]; d = csub(u, e[5]); e[1] = cadd(u, e[5]); e[5] = cmul(d, w1);
        u = e[2]; d = csub(u, e[6]); e[2] = cadd(u, e[6]); e[6] = cmul(d, w2t);
        u = e[3]; d = csub(u, e[7]); e[3] = cadd(u, e[7]); e[7] = cmul(d, w3);
    }
    fwd8_bc(e, w);
}
// First pass variant: inputs e[4..7] are zero (zero-padded upper half).
__device__ __forceinline__ void fwd8_zero(float2 e[8], float2 w) {
    float2 w1  = make_float2(R2C * (w.x + w.y), R2C * (w.y - w.x));
    float2 w2t = cmulnegi(w);
    float2 w3  = cmulnegi(w1);
    e[4] = cmul(e[0], w); e[5] = cmul(e[1], w1);
    e[6] = cmul(e[2], w2t); e[7] = cmul(e[3], w3);
    fwd8_bc(e, w);
}

// ---- inverse radix-8 (DIT halves {s,2s,4s}), v = exp(+2pi i (t mod s)/(8s)) ----
__device__ __forceinline__ void inv8(float2 e[8], float2 v) {
    float2 v2 = cmul(v, v);
    float2 v4 = cmul(v2, v2);
    {   float2 u, tv;
        u = e[0]; tv = cmul(e[1], v4); e[0] = cadd(u, tv); e[1] = csub(u, tv);
        u = e[2]; tv = cmul(e[3], v4); e[2] = cadd(u, tv); e[3] = csub(u, tv);
        u = e[4]; tv = cmul(e[5], v4); e[4] = cadd(u, tv); e[5] = csub(u, tv);
        u = e[6]; tv = cmul(e[7], v4); e[6] = cadd(u, tv); e[7] = csub(u, tv);
    }
    float2 v2i = cmuli(v2);
    {   float2 u, tv;
        u = e[0]; tv = cmul(e[2], v2);  e[0] = cadd(u, tv); e[2] = csub(u, tv);
        u = e[1]; tv = cmul(e[3], v2i); e[1] = cadd(u, tv); e[3] = csub(u, tv);
        u = e[4]; tv = cmul(e[6], v2);  e[4] = cadd(u, tv); e[6] = csub(u, tv);
        u = e[5]; tv = cmul(e[7], v2i); e[5] = cadd(u, tv); e[7] = csub(u, tv);
    }
    float2 q1 = make_float2(R2C * (v.x - v.y), R2C * (v.x + v.y)); // v*V8^1
    float2 q2 = cmuli(v);                                           // v*V8^2
    float2 q3 = cmuli(q1);                                          // v*V8^3
    {   float2 u, tv;
        u = e[0]; tv = cmul(e[4], v);  e[0] = cadd(u, tv); e[4] = csub(u, tv);
        u = e[1]; tv = cmul(e[5], q1); e[1] = cadd(u, tv); e[5] = csub(u, tv);
        u = e[2]; tv = cmul(e[6], q2); e[2] = cadd(u, tv); e[6] = csub(u, tv);
        u = e[3]; tv = cmul(e[7], q3); e[3] = cadd(u, tv); e[7] = csub(u, tv);
    }
}
// Specialized inv8 with v = 1 (s=1 pass: all twiddles are constants).
__device__ __forceinline__ void inv8_unit(float2 e[8]) {
    {   float2 a, b;
        a = e[0]; b = e[1]; e[0] = cadd(a, b); e[1] = csub(a, b);
        a = e[2]; b = e[3]; e[2] = cadd(a, b); e[3] = csub(a, b);
        a = e[4]; b = e[5]; e[4] = cadd(a, b); e[5] = csub(a, b);
        a = e[6]; b = e[7]; e[6] = cadd(a, b); e[7] = csub(a, b);
    }
    {   float2 u, tv;
        u = e[0]; tv = e[2];        e[0] = cadd(u, tv); e[2] = csub(u, tv);
        u = e[1]; tv = cmuli(e[3]); e[1] = cadd(u, tv); e[3] = csub(u, tv);
        u = e[4]; tv = e[6];        e[4] = cadd(u, tv); e[6] = csub(u, tv);
        u = e[5]; tv = cmuli(e[7]); e[5] = cadd(u, tv); e[7] = csub(u, tv);
    }
    {   float2 u, tv;
        u = e[0]; tv = e[4];        e[0] = cadd(u, tv); e[4] = csub(u, tv);
        u = e[1]; tv = make_float2(R2C * (e[5].x - e[5].y), R2C * (e[5].x + e[5].y));
                                    e[1] = cadd(u, tv); e[5] = csub(u, tv);
        u = e[2]; tv = cmuli(e[6]); e[2] = cadd(u, tv); e[6] = csub(u, tv);
        u = e[3]; tv = make_float2(R2C * (-e[7].x - e[7].y), R2C * (e[7].x - e[7].y));
                                    e[3] = cadd(u, tv); e[7] = csub(u, tv);
    }
}

// Twiddles recomputed inside each pass (1 sincos) so nothing persists across
// barriers except kspec/xr: this is the anti-spill measure.
template<int S>
__device__ __forceinline__ void pass_fwd(float2* A, int t) {
    constexpr int L = (S == 1024) ? 10 : (S == 128) ? 7 : (S == 16) ? 4 : 1;
    float2 w;
    sincos_rev(-(float)(t & (S - 1)) * (1.0f / (8.0f * (float)S)), w.y, w.x);
    const int base = ((t >> L) << (L + 3)) | (t & (S - 1));
    float2 e[8];
    #pragma unroll
    for (int j = 0; j < 8; ++j) e[j] = A[SW(base + j * S)];
    fwd8(e, w);
    #pragma unroll
    for (int j = 0; j < 8; ++j) A[SW(base + j * S)] = e[j];
}

template<int S>
__device__ __forceinline__ void pass_inv(float2* A, int t) {
    constexpr int L = (S == 512) ? 9 : (S == 64) ? 6 : 3;
    float2 v;
    sincos_rev((float)(t & (S - 1)) * (1.0f / (8.0f * (float)S)), v.y, v.x);
    const int base = ((t >> L) << (L + 3)) | (t & (S - 1));
    float2 e[8];
    #pragma unroll
    for (int j = 0; j < 8; ++j) e[j] = A[SW(base + j * S)];
    inv8(e, v);
    #pragma unroll
    for (int j = 0; j < 8; ++j) A[SW(base + j * S)] = e[j];
}

__global__ void
__attribute__((amdgpu_flat_work_group_size(NTHR, NTHR), amdgpu_waves_per_eu(4, 4)))
fftconv_kernel(const float* __restrict__ x,
               const float* __restrict__ kin,
               const float* __restrict__ Din,
               float* __restrict__ out)
{
    __shared__ float2 A[NFFT];   // 64 KiB

    const int t = threadIdx.x;
    const int h = blockIdx.x;

    const float* kp = kin + (size_t)h * (size_t)Ldim;   // C = 1
    const float  Dh = Din[h];
    const float  invN = 1.0f / (float)NFFT;

    // ================= K: forward FFT, spectrum -> kspec regs =================
    {
        float2 w;                                   // exp(-2pi i t/8192)
        sincos_rev(-(float)t * (1.0f / 8192.0f), w.y, w.x);
        float2 e[8];
        #pragma unroll
        for (int j = 0; j < 4; ++j) e[j] = make_float2(kp[t + 1024 * j], 0.0f);
        fwd8_zero(e, w);
        #pragma unroll
        for (int j = 0; j < 8; ++j) A[SW(t + 1024 * j)] = e[j];
    }
    __syncthreads();
    pass_fwd<128>(A, t);  __syncthreads();
    pass_fwd<16>(A, t);   __syncthreads();
    pass_fwd<2>(A, t);    __syncthreads();
    float2 kspec[8];
    {
        float2 c[8];
        #pragma unroll
        for (int j = 0; j < 8; ++j) c[j] = A[SW(8 * t + j)];
        #pragma unroll
        for (int u2 = 0; u2 < 4; ++u2) {         // fwd half=1 (twiddle-free) + 1/N
            float2 a = c[2 * u2], b = c[2 * u2 + 1];
            kspec[2 * u2]     = make_float2((a.x + b.x) * invN, (a.y + b.y) * invN);
            kspec[2 * u2 + 1] = make_float2((a.x - b.x) * invN, (a.y - b.y) * invN);
        }
    }

    // ================= batch pairs =================
    for (int p = 0; p < 2; ++p) {
        const float* xp0 = x + ((size_t)(2 * p)     * Hdim + h) * (size_t)Ldim;
        const float* xp1 = x + ((size_t)(2 * p + 1) * Hdim + h) * (size_t)Ldim;
        float xr0[4], xr1[4];

        __syncthreads();   // prior reads of A (kspec stash) complete
        {
            float2 w;                               // exp(-2pi i t/8192)
            sincos_rev(-(float)t * (1.0f / 8192.0f), w.y, w.x);
            float2 e[8];
            #pragma unroll
            for (int j = 0; j < 4; ++j) {
                float a = xp0[t + 1024 * j], b = xp1[t + 1024 * j];
                xr0[j] = a; xr1[j] = b;
                e[j] = make_float2(a, b);        // z = x_b0 + i x_b1
            }
            fwd8_zero(e, w);
            #pragma unroll
            for (int j = 0; j < 8; ++j) A[SW(t + 1024 * j)] = e[j];
        }
        __syncthreads();
        pass_fwd<128>(A, t);  __syncthreads();
        pass_fwd<16>(A, t);   __syncthreads();
        pass_fwd<2>(A, t);    __syncthreads();
        {   // mid: fwd half=1 + pointwise*Kspec + inv halves {1,2,4}, in regs
            float2 c[8];
            #pragma unroll
            for (int j = 0; j < 8; ++j) c[j] = A[SW(8 * t + j)];
            #pragma unroll
            for (int u2 = 0; u2 < 4; ++u2) {
                float2 a = c[2 * u2], b = c[2 * u2 + 1];
                c[2 * u2] = cadd(a, b); c[2 * u2 + 1] = csub(a, b);
            }
            #pragma unroll
            for (int j = 0; j < 8; ++j) c[j] = cmul(c[j], kspec[j]);
            inv8_unit(c);
            #pragma unroll
            for (int j = 0; j < 8; ++j) A[SW(8 * t + j)] = c[j];
        }
        __syncthreads();
        pass_inv<8>(A, t);    __syncthreads();
        pass_inv<64>(A, t);   __syncthreads();
        pass_inv<512>(A, t);  __syncthreads();
        {   // epilogue: last DIT stage (half=4096), low half only, + D*x skip
            float* op0 = out + ((size_t)(2 * p)     * Hdim + h) * (size_t)Ldim;
            float* op1 = out + ((size_t)(2 * p + 1) * Hdim + h) * (size_t)Ldim;
            float2 vf;                              // exp(+2pi i t/8192)
            sincos_rev((float)t * (1.0f / 8192.0f), vf.y, vf.x);
            float2 tws[4];
            tws[0] = vf;
            tws[1] = make_float2(R2C * (vf.x - vf.y), R2C * (vf.x + vf.y)); // vf*V8
            tws[2] = cmuli(vf);
            tws[3] = cmuli(tws[1]);
            #pragma unroll
            for (int r = 0; r < 4; ++r) {
                int u = t + 1024 * r;
                float2 lo = A[SW(u)];
                float2 hi = cmul(A[SW(u + 4096)], tws[r]);
                op0[u] = (lo.x + hi.x) + Dh * xr0[r];
                op1[u] = (lo.y + hi.y) + Dh * xr1[r];
            }
        }
        // Epilogue reads exactly this thread's own slots (t+1024j), which are
        // also what the next pair's z-store writes -> loop-top barrier suffices.
    }
}

extern "C" void kernel_launch(void* const* d_in, const int* in_sizes, int n_in,
                              void* d_out, int out_size, void* d_ws, size_t ws_size,
                              hipStream_t stream)
{
    const float* x  = (const float*)d_in[0];
    const float* k  = (const float*)d_in[1];
    const float* D  = (const float*)d_in[2];
    float* out = (float*)d_out;

    dim3 grid(Hdim);          // one block per h
    dim3 block(NTHR);
    hipLaunchKernelGGL(fftconv_kernel, grid, block, 0, stream, x, k, D, out);
}

// Round 7
// 270.872 us; speedup vs baseline: 1.2804x; 1.2804x over previous
//
#include <hip/hip_runtime.h>

// y[b,h,l] = sum_{m<=l} x[b,h,m] k[h,l-m] + D[h] x[b,h,l]   (C = 1)
// One block per h (1024 threads, 8 complex elems/thread in registers).
// 8192-pt FFT as 5 register passes (radix-8 x4 + radix-2), 4 LDS exchanges.
// K = FFT(k) once -> Kb in LDS (pre-scaled 1/N). Batch pairs (0,1),(2,3)
// via z = x_b0 + i x_b1; ifft(FFT(z)*K) = y_b0 + i y_b1.
// Fusions: fwd pass 1 reads global (upper half zero); mid = fwd half=1 +
// pointwise + inv halves {1,2,4} in regs; last inv stage fused with epilogue.
//
// Resource model (r3-r6): the backend derives its occupancy target from LDS
// capacity. At 64 KiB LDS it targets 8 waves/EU -> VGPR pinned to 64 ->
// ~1.2 GB of spill traffic per dispatch. Using 128 KiB LDS (1 block/CU)
// drops the target to 4 waves/EU -> 128-VGPR budget. The second 64 KiB
// buffer holds the K spectrum, which also removes 16 persistent VGPRs.
#define Bdim 4
#define Hdim 1024
#define Ldim 4096
#define NFFT 8192
#define NTHR 1024
#define R2C 0.70710678118654752440f

// LDS float2-index swizzle: minimal-round b64 access for all strides used.
__device__ __forceinline__ int SW(int i) { return i ^ ((i >> 4) & 15); }

// v_sin_f32 / v_cos_f32 take input in REVOLUTIONS (D = sin(S0*2pi)).
__device__ __forceinline__ void sincos_rev(float f, float& s, float& c) {
#if __has_builtin(__builtin_amdgcn_sinf) && __has_builtin(__builtin_amdgcn_cosf)
    s = __builtin_amdgcn_sinf(f);
    c = __builtin_amdgcn_cosf(f);
#else
    __sincosf(f * 6.28318530717958647692f, &s, &c);
#endif
}

__device__ __forceinline__ float2 cadd(float2 a, float2 b) { return make_float2(a.x + b.x, a.y + b.y); }
__device__ __forceinline__ float2 csub(float2 a, float2 b) { return make_float2(a.x - b.x, a.y - b.y); }
__device__ __forceinline__ float2 cmul(float2 a, float2 b) {
    return make_float2(a.x * b.x - a.y * b.y, a.x * b.y + a.y * b.x);
}
__device__ __forceinline__ float2 cmuli(float2 a)    { return make_float2(-a.y, a.x); }  // a * (+i)
__device__ __forceinline__ float2 cmulnegi(float2 a) { return make_float2(a.y, -a.x); }  // a * (-i)

// ---- forward radix-8 (DIF halves {4s,2s,s}), w = exp(-2pi i (t mod s)/(8s)) ----
__device__ __forceinline__ void fwd8_bc(float2 e[8], float2 w) {
    float2 w2  = cmul(w, w);        // W_{4s}^{qm}
    float2 w2n = cmulnegi(w2);
    {   float2 u, d;
        u = e[0]; d = csub(u, e[2]); e[0] = cadd(u, e[2]); e[2] = cmul(d, w2);
        u = e[1]; d = csub(u, e[3]); e[1] = cadd(u, e[3]); e[3] = cmul(d, w2n);
        u = e[4]; d = csub(u, e[6]); e[4] = cadd(u, e[6]); e[6] = cmul(d, w2);
        u = e[5]; d = csub(u, e[7]); e[5] = cadd(u, e[7]); e[7] = cmul(d, w2n);
    }
    float2 w4 = cmul(w2, w2);       // W_{2s}^{qm}
    {   float2 u, d;
        u = e[0]; d = csub(u, e[1]); e[0] = cadd(u, e[1]); e[1] = cmul(d, w4);
        u = e[2]; d = csub(u, e[3]); e[2] = cadd(u, e[3]); e[3] = cmul(d, w4);
        u = e[4]; d = csub(u, e[5]); e[4] = cadd(u, e[5]); e[5] = cmul(d, w4);
        u = e[6]; d = csub(u, e[7]); e[6] = cadd(u, e[7]); e[7] = cmul(d, w4);
    }
}
__device__ __forceinline__ void fwd8(float2 e[8], float2 w) {
    float2 w1  = make_float2(R2C * (w.x + w.y), R2C * (w.y - w.x)); // w*W8^1
    float2 w2t = cmulnegi(w);                                        // w*W8^2
    float2 w3  = cmulnegi(w1);                                       // w*W8^3
    {   float2 u, d;
        u = e[0]; d = csub(u, e[4]); e[0] = cadd(u, e[4]); e[4] = cmul(d, w);
        u = e[1]; d = csub(u, e[5]); e[1] = cadd(u, e[5]); e[5] = cmul(d, w1);
        u = e[2]; d = csub(u, e[6]); e[2] = cadd(u, e[6]); e[6] = cmul(d, w2t);
        u = e[3]; d = csub(u, e[7]); e[3] = cadd(u, e[7]); e[7] = cmul(d, w3);
    }
    fwd8_bc(e, w);
}
// First pass variant: inputs e[4..7] are zero (zero-padded upper half).
__device__ __forceinline__ void fwd8_zero(float2 e[8], float2 w) {
    float2 w1  = make_float2(R2C * (w.x + w.y), R2C * (w.y - w.x));
    float2 w2t = cmulnegi(w);
    float2 w3  = cmulnegi(w1);
    e[4] = cmul(e[0], w); e[5] = cmul(e[1], w1);
    e[6] = cmul(e[2], w2t); e[7] = cmul(e[3], w3);
    fwd8_bc(e, w);
}

// ---- inverse radix-8 (DIT halves {s,2s,4s}), v = exp(+2pi i (t mod s)/(8s)) ----
__device__ __forceinline__ void inv8(float2 e[8], float2 v) {
    float2 v2 = cmul(v, v);
    float2 v4 = cmul(v2, v2);
    {   float2 u, tv;
        u = e[0]; tv = cmul(e[1], v4); e[0] = cadd(u, tv); e[1] = csub(u, tv);
        u = e[2]; tv = cmul(e[3], v4); e[2] = cadd(u, tv); e[3] = csub(u, tv);
        u = e[4]; tv = cmul(e[5], v4); e[4] = cadd(u, tv); e[5] = csub(u, tv);
        u = e[6]; tv = cmul(e[7], v4); e[6] = cadd(u, tv); e[7] = csub(u, tv);
    }
    float2 v2i = cmuli(v2);
    {   float2 u, tv;
        u = e[0]; tv = cmul(e[2], v2);  e[0] = cadd(u, tv); e[2] = csub(u, tv);
        u = e[1]; tv = cmul(e[3], v2i); e[1] = cadd(u, tv); e[3] = csub(u, tv);
        u = e[4]; tv = cmul(e[6], v2);  e[4] = cadd(u, tv); e[6] = csub(u, tv);
        u = e[5]; tv = cmul(e[7], v2i); e[5] = cadd(u, tv); e[7] = csub(u, tv);
    }
    float2 q1 = make_float2(R2C * (v.x - v.y), R2C * (v.x + v.y)); // v*V8^1
    float2 q2 = cmuli(v);                                           // v*V8^2
    float2 q3 = cmuli(q1);                                          // v*V8^3
    {   float2 u, tv;
        u = e[0]; tv = cmul(e[4], v);  e[0] = cadd(u, tv); e[4] = csub(u, tv);
        u = e[1]; tv = cmul(e[5], q1); e[1] = cadd(u, tv); e[5] = csub(u, tv);
        u = e[2]; tv = cmul(e[6], q2); e[2] = cadd(u, tv); e[6] = csub(u, tv);
        u = e[3]; tv = cmul(e[7], q3); e[3] = cadd(u, tv); e[7] = csub(u, tv);
    }
}
// Specialized inv8 with v = 1 (s=1 pass: all twiddles are constants).
__device__ __forceinline__ void inv8_unit(float2 e[8]) {
    {   float2 a, b;
        a = e[0]; b = e[1]; e[0] = cadd(a, b); e[1] = csub(a, b);
        a = e[2]; b = e[3]; e[2] = cadd(a, b); e[3] = csub(a, b);
        a = e[4]; b = e[5]; e[4] = cadd(a, b); e[5] = csub(a, b);
        a = e[6]; b = e[7]; e[6] = cadd(a, b); e[7] = csub(a, b);
    }
    {   float2 u, tv;
        u = e[0]; tv = e[2];        e[0] = cadd(u, tv); e[2] = csub(u, tv);
        u = e[1]; tv = cmuli(e[3]); e[1] = cadd(u, tv); e[3] = csub(u, tv);
        u = e[4]; tv = e[6];        e[4] = cadd(u, tv); e[6] = csub(u, tv);
        u = e[5]; tv = cmuli(e[7]); e[5] = cadd(u, tv); e[7] = csub(u, tv);
    }
    {   float2 u, tv;
        u = e[0]; tv = e[4];        e[0] = cadd(u, tv); e[4] = csub(u, tv);
        u = e[1]; tv = make_float2(R2C * (e[5].x - e[5].y), R2C * (e[5].x + e[5].y));
                                    e[1] = cadd(u, tv); e[5] = csub(u, tv);
        u = e[2]; tv = cmuli(e[6]); e[2] = cadd(u, tv); e[6] = csub(u, tv);
        u = e[3]; tv = make_float2(R2C * (-e[7].x - e[7].y), R2C * (e[7].x - e[7].y));
                                    e[3] = cadd(u, tv); e[7] = csub(u, tv);
    }
}

// Twiddles recomputed inside each pass (1 sincos) so nothing persists across
// barriers except xr: keeps live-across-barrier state tiny.
template<int S>
__device__ __forceinline__ void pass_fwd(float2* A, int t) {
    constexpr int L = (S == 1024) ? 10 : (S == 128) ? 7 : (S == 16) ? 4 : 1;
    float2 w;
    sincos_rev(-(float)(t & (S - 1)) * (1.0f / (8.0f * (float)S)), w.y, w.x);
    const int base = ((t >> L) << (L + 3)) | (t & (S - 1));
    float2 e[8];
    #pragma unroll
    for (int j = 0; j < 8; ++j) e[j] = A[SW(base + j * S)];
    fwd8(e, w);
    #pragma unroll
    for (int j = 0; j < 8; ++j) A[SW(base + j * S)] = e[j];
}

template<int S>
__device__ __forceinline__ void pass_inv(float2* A, int t) {
    constexpr int L = (S == 512) ? 9 : (S == 64) ? 6 : 3;
    float2 v;
    sincos_rev((float)(t & (S - 1)) * (1.0f / (8.0f * (float)S)), v.y, v.x);
    const int base = ((t >> L) << (L + 3)) | (t & (S - 1));
    float2 e[8];
    #pragma unroll
    for (int j = 0; j < 8; ++j) e[j] = A[SW(base + j * S)];
    inv8(e, v);
    #pragma unroll
    for (int j = 0; j < 8; ++j) A[SW(base + j * S)] = e[j];
}

__global__ void
__attribute__((amdgpu_flat_work_group_size(NTHR, NTHR)))
fftconv_kernel(const float* __restrict__ x,
               const float* __restrict__ kin,
               const float* __restrict__ Din,
               float* __restrict__ out)
{
    __shared__ float2 A[NFFT];    // 64 KiB working buffer
    __shared__ float2 Kb[NFFT];   // 64 KiB K-spectrum (total 128 KiB -> 1 blk/CU)

    const int t = threadIdx.x;
    const int h = blockIdx.x;

    const float* kp = kin + (size_t)h * (size_t)Ldim;   // C = 1
    const float  Dh = Din[h];
    const float  invN = 1.0f / (float)NFFT;

    // ================= K: forward FFT -> Kb (pre-scaled by 1/N) =================
    {
        float2 w;                                   // exp(-2pi i t/8192)
        sincos_rev(-(float)t * (1.0f / 8192.0f), w.y, w.x);
        float2 e[8];
        #pragma unroll
        for (int j = 0; j < 4; ++j) e[j] = make_float2(kp[t + 1024 * j], 0.0f);
        fwd8_zero(e, w);
        #pragma unroll
        for (int j = 0; j < 8; ++j) A[SW(t + 1024 * j)] = e[j];
    }
    __syncthreads();
    pass_fwd<128>(A, t);  __syncthreads();
    pass_fwd<16>(A, t);   __syncthreads();
    pass_fwd<2>(A, t);    __syncthreads();
    {   // fwd half=1 stage (twiddle-free) + 1/N, written to Kb (own slots;
        // later reads are by the same thread -> no barrier needed for Kb).
        float2 c[8];
        #pragma unroll
        for (int j = 0; j < 8; ++j) c[j] = A[SW(8 * t + j)];
        #pragma unroll
        for (int u2 = 0; u2 < 4; ++u2) {
            float2 a = c[2 * u2], b = c[2 * u2 + 1];
            Kb[SW(8 * t + 2 * u2)]     = make_float2((a.x + b.x) * invN, (a.y + b.y) * invN);
            Kb[SW(8 * t + 2 * u2 + 1)] = make_float2((a.x - b.x) * invN, (a.y - b.y) * invN);
        }
    }

    // ================= batch pairs =================
    for (int p = 0; p < 2; ++p) {
        const float* xp0 = x + ((size_t)(2 * p)     * Hdim + h) * (size_t)Ldim;
        const float* xp1 = x + ((size_t)(2 * p + 1) * Hdim + h) * (size_t)Ldim;
        float xr0[4], xr1[4];

        __syncthreads();   // prior reads of A complete before overwriting
        {
            float2 w;                               // exp(-2pi i t/8192)
            sincos_rev(-(float)t * (1.0f / 8192.0f), w.y, w.x);
            float2 e[8];
            #pragma unroll
            for (int j = 0; j < 4; ++j) {
                float a = xp0[t + 1024 * j], b = xp1[t + 1024 * j];
                xr0[j] = a; xr1[j] = b;
                e[j] = make_float2(a, b);        // z = x_b0 + i x_b1
            }
            fwd8_zero(e, w);
            #pragma unroll
            for (int j = 0; j < 8; ++j) A[SW(t + 1024 * j)] = e[j];
        }
        __syncthreads();
        pass_fwd<128>(A, t);  __syncthreads();
        pass_fwd<16>(A, t);   __syncthreads();
        pass_fwd<2>(A, t);    __syncthreads();
        {   // mid: fwd half=1 + pointwise*Kb + inv halves {1,2,4}, in regs
            float2 c[8];
            #pragma unroll
            for (int j = 0; j < 8; ++j) c[j] = A[SW(8 * t + j)];
            #pragma unroll
            for (int u2 = 0; u2 < 4; ++u2) {
                float2 a = c[2 * u2], b = c[2 * u2 + 1];
                c[2 * u2] = cadd(a, b); c[2 * u2 + 1] = csub(a, b);
            }
            #pragma unroll
            for (int j = 0; j < 8; ++j) c[j] = cmul(c[j], Kb[SW(8 * t + j)]);
            inv8_unit(c);
            #pragma unroll
            for (int j = 0; j < 8; ++j) A[SW(8 * t + j)] = c[j];
        }
        __syncthreads();
        pass_inv<8>(A, t);    __syncthreads();
        pass_inv<64>(A, t);   __syncthreads();
        pass_inv<512>(A, t);  __syncthreads();
        {   // epilogue: last DIT stage (half=4096), low half only, + D*x skip
            float* op0 = out + ((size_t)(2 * p)     * Hdim + h) * (size_t)Ldim;
            float* op1 = out + ((size_t)(2 * p + 1) * Hdim + h) * (size_t)Ldim;
            float2 vf;                              // exp(+2pi i t/8192)
            sincos_rev((float)t * (1.0f / 8192.0f), vf.y, vf.x);
            float2 tws[4];
            tws[0] = vf;
            tws[1] = make_float2(R2C * (vf.x - vf.y), R2C * (vf.x + vf.y)); // vf*V8
            tws[2] = cmuli(vf);
            tws[3] = cmuli(tws[1]);
            #pragma unroll
            for (int r = 0; r < 4; ++r) {
                int u = t + 1024 * r;
                float2 lo = A[SW(u)];
                float2 hi = cmul(A[SW(u + 4096)], tws[r]);
                op0[u] = (lo.x + hi.x) + Dh * xr0[r];
                op1[u] = (lo.y + hi.y) + Dh * xr1[r];
            }
        }
        // Epilogue reads this thread's own slots (t+1024j), which are also
        // what the next pair's z-store writes -> loop-top barrier suffices.
    }
}

extern "C" void kernel_launch(void* const* d_in, const int* in_sizes, int n_in,
                              void* d_out, int out_size, void* d_ws, size_t ws_size,
                              hipStream_t stream)
{
    const float* x  = (const float*)d_in[0];
    const float* k  = (const float*)d_in[1];
    const float* D  = (const float*)d_in[2];
    float* out = (float*)d_out;

    dim3 grid(Hdim);          // one block per h
    dim3 block(NTHR);
    hipLaunchKernelGGL(fftconv_kernel, grid, block, 0, stream, x, k, D, out);
}